// Round 3
// baseline (307.085 us; speedup 1.0000x reference)
//
#include <hip/hip_runtime.h>
#include <stdint.h>

// Problem constants
#define B_   8
#define C_   256
#define N_   2304          // 48*48 spatial
#define HID  128
#define O3   384           // 3*HID
#define NH   4
#define SCALE 0.0625f      // 256^-0.5
#define QPRE 0.09016844f   // SCALE * log2(e): q pre-scale so p = exp2(q.k)

typedef unsigned short u16;
typedef short  bf8  __attribute__((ext_vector_type(8)));   // 8 bf16 (4 VGPRs) MFMA A/B frag
typedef float  f4   __attribute__((ext_vector_type(4)));   // MFMA C/D frag
typedef u16    u16x8 __attribute__((ext_vector_type(8)));

#define MFMA(a,b,c) __builtin_amdgcn_mfma_f32_16x16x32_bf16((a),(b),(c),0,0,0)

static __device__ __forceinline__ u16 f2bf(float f){
    union { float f; unsigned int i; } v; v.f = f;
    unsigned int r = v.i + 0x7FFFu + ((v.i >> 16) & 1u);   // round-to-nearest-even
    return (u16)(r >> 16);
}
static __device__ __forceinline__ float fexp2(float x){
#if __has_builtin(__builtin_amdgcn_exp2f)
    return __builtin_amdgcn_exp2f(x);
#else
    return __expf(x * 0.69314718f);
#endif
}
static __device__ __forceinline__ u16 hi16(float f){       // truncating f32->bf16
    union { float f; unsigned int i; } v; v.f = f;
    return (u16)(v.i >> 16);
}

// ---------------------------------------------------------------------------
// K0a: convert embed weights fp32 -> bf16.
__global__ __launch_bounds__(256) void k_wcvt(const float* __restrict__ w0,
                                              const float* __restrict__ w1,
                                              u16* __restrict__ Wbf){
    int s = blockIdx.y;
    const float* w = s ? w1 : w0;
    u16* o = Wbf + (size_t)s * (O3 * C_);
    int idx = (blockIdx.x * 256 + threadIdx.x) * 4;
    float4 v = *reinterpret_cast<const float4*>(&w[idx]);
    o[idx+0] = f2bf(v.x); o[idx+1] = f2bf(v.y);
    o[idx+2] = f2bf(v.z); o[idx+3] = f2bf(v.w);
}

// K0b: w_eff^T[s][oc][hc] = sum_head out_w_s[head*HID+hc][oc]  (heads identical)
__global__ __launch_bounds__(256) void k_weff(const float* __restrict__ w0,
                                              const float* __restrict__ w1,
                                              u16* __restrict__ weff){
    int gid = blockIdx.x * 256 + threadIdx.x;   // 2*128*256 = 65536
    int oc = gid & 255, hc = (gid >> 8) & 127, s = gid >> 15;
    const float* w = s ? w1 : w0;
    float acc = 0.f;
    #pragma unroll
    for (int h = 0; h < NH; ++h) acc += w[(h*HID + hc)*C_ + oc];
    weff[(s*C_ + oc)*HID + hc] = f2bf(acc);
}

// ---------------------------------------------------------------------------
// K1a: transpose+convert X[bs][c][n] fp32 -> Xt[bs][n][c] bf16 (Xt in d_out)
__global__ __launch_bounds__(256) void k_transpose(const float* __restrict__ x0,
                                                   const float* __restrict__ x1,
                                                   u16* __restrict__ Xt){
    __shared__ __align__(16) u16 tile[64][72];
    int z = blockIdx.z, b = z >> 1, s = z & 1;
    const float* X = (s ? x1 : x0) + (size_t)b * (C_ * N_);
    u16* out = Xt + (size_t)z * (N_ * C_);
    int n0 = blockIdx.x * 64, c0 = blockIdx.y * 64;
    int t = threadIdx.x;
    int lr = t >> 4, lc = (t & 15) * 4;
    #pragma unroll
    for (int rep = 0; rep < 4; ++rep){
        int c = lr + rep * 16;
        float4 v = *reinterpret_cast<const float4*>(&X[(size_t)(c0 + c) * N_ + n0 + lc]);
        tile[c][lc+0] = f2bf(v.x); tile[c][lc+1] = f2bf(v.y);
        tile[c][lc+2] = f2bf(v.z); tile[c][lc+3] = f2bf(v.w);
    }
    __syncthreads();
    int row = t >> 3, col8 = (t & 7) * 8;
    #pragma unroll
    for (int rep = 0; rep < 2; ++rep){
        int n = row + rep * 32;
        u16x8 v;
        #pragma unroll
        for (int j = 0; j < 8; ++j) v[j] = tile[col8 + j][n];
        *reinterpret_cast<u16x8*>(&out[(size_t)(n0 + n) * C_ + c0 + col8]) = v;
    }
}

// ---------------------------------------------------------------------------
// K1b: embed GEMM.  Q pre-scaled by QPRE.  K/V written in fragment-coalesced
// chunk-interleaved layouts (16 B contiguous per lane per MFMA fragment):
//   Kc[z][nc][cc][n&63][8] : elem (n,h) at ((n>>6)*16 + (h>>3))*512 + (n&63)*8 + (h&7)
//   Vc[z][nc][pc][hc][8]   : elem (hc,n) at ((n>>6)*8 + ((n>>3)&7))*1024 + hc*8 + (n&7)
__global__ __launch_bounds__(256, 4) void k_embed(const u16* __restrict__ Xt,
        const u16* __restrict__ Wbf,
        const float* __restrict__ b0, const float* __restrict__ b1,
        u16* __restrict__ Qt, u16* __restrict__ Kc, u16* __restrict__ Vc){
    int z = blockIdx.z, s = z & 1;
    const u16* W = Wbf + (size_t)s * (O3 * C_);
    const float* bias = s ? b1 : b0;
    const u16* Xb = Xt + (size_t)z * (N_ * C_);
    int lane = threadIdx.x & 63, wave = threadIdx.x >> 6;
    int l16 = lane & 15, quad = lane >> 4;
    int o0 = blockIdx.y * 64 + wave * 16;
    int n0 = blockIdx.x * 64;
    f4 acc[4] = {f4{0,0,0,0}, f4{0,0,0,0}, f4{0,0,0,0}, f4{0,0,0,0}};
    #pragma unroll
    for (int kk = 0; kk < 8; ++kk){           // K = 256 = 8 * 32
        bf8 a = *reinterpret_cast<const bf8*>(&W[(o0 + l16) * C_ + kk*32 + quad*8]);
        #pragma unroll
        for (int nt = 0; nt < 4; ++nt){
            bf8 bb = *reinterpret_cast<const bf8*>(&Xb[(size_t)(n0 + nt*16 + l16) * C_ + kk*32 + quad*8]);
            acc[nt] = MFMA(a, bb, acc[nt]);
        }
    }
    size_t zq = (size_t)z * (N_ * HID);
    #pragma unroll
    for (int nt = 0; nt < 4; ++nt){
        int n = n0 + nt*16 + l16;
        #pragma unroll
        for (int r = 0; r < 4; ++r){
            int o = o0 + quad*4 + r;
            float e = acc[nt][r] + bias[o];
            if (o < HID){
                Qt[zq + (size_t)n*HID + o] = f2bf(e * QPRE);
            } else if (o < 2*HID){
                int h = o - HID;
                Kc[zq + ((n>>6)*16 + (h>>3))*512 + ((n&63)<<3) + (h&7)] = f2bf(e);
            } else {
                int hc = o - 2*HID;
                Vc[zq + ((n>>6)*8 + ((n>>3)&7))*1024 + (hc<<3) + (n&7)] = f2bf(e);
            }
        }
    }
}

// ---------------------------------------------------------------------------
// K2 (fused): max-free flash attention + output projection + residual.
//   v4: NO LDS staging of K/V and NO main-loop barriers.  K+V per z = 1.2 MB,
//   pinned to one XCD's 4 MB L2 by the swizzle (FETCH_SIZE ~= unique bytes
//   proves L2 residency), so the Kc/Vc layouts let each MFMA fragment load
//   directly global->VGPR as one coalesced 16B/lane dwordx4 (L2 hit).
//   Per-chunk sync is per-wave vmcnt/lgkmcnt only; waves drift freely.
//   K frags for chunk nc+1 are refilled right after QK consumes them; V frag
//   loads are split 4+4 around the exp/P phase to bound register pressure.
//   P tile stays per-wave in LDS (pad 42).  Epilogue (cross-kw fold) as v3.
// LDS map (bytes):
//   main loop: [0,10752) P tiles (4 waves x 32x42 u16)
//   epilogue : [0,33792) partial O 64x132 f32 | [33792,34048) rowsum 64 f32
//              then [0,17408) H tile 64x136 u16 (after fold barriers)
__global__ __launch_bounds__(256, 3) void k_attn_out(const u16* __restrict__ Qt,
        const u16* __restrict__ Kc, const u16* __restrict__ Vc,
        const u16* __restrict__ weff,
        const float* __restrict__ ob0, const float* __restrict__ ob1,
        const float* __restrict__ x0, const float* __restrict__ x1,
        float* __restrict__ out){
    __shared__ __align__(16) u16 lds[17024];           // 34048 B
    int bx = blockIdx.x;                      // 576 = 8 XCD * 72
    int xcd = bx & 7, t = bx >> 3;
    int z  = xcd*2 + (t >= 36 ? 1 : 0);       // XCD x serves z in {2x,2x+1}
    int mt = (t >= 36) ? (t - 36) : t;
    int b = z >> 1, s = z & 1;
    const u16* Q = Qt + (size_t)(b*2 + (1 - s)) * (N_ * HID);
    const u16* K = Kc + (size_t)(b*2 + s)       * (N_ * HID);
    const u16* V = Vc + (size_t)(b*2 + s)       * (N_ * HID);
    const u16* Wf   = weff + (size_t)s * (C_ * HID);
    const float* bias = s ? ob1 : ob0;
    const float* X = (s ? x1 : x0) + (size_t)b * (C_ * N_);
    float* O = out + (size_t)s * ((size_t)B_ * C_ * N_) + (size_t)b * (C_ * N_);
    int lane = threadIdx.x & 63, wave = threadIdx.x >> 6;
    int l16 = lane & 15, quad = lane >> 4;
    int rw = wave & 1, kw = wave >> 1;        // row-half, key-half
    int m0 = mt * 64 + rw * 32;

    // per-lane fragment base pointers into the chunk-interleaved K/V layouts;
    // chunk stride is 8192 u16 (16 KB) for both.
    // K frag (kk,kt): kp[nc*8192 + kk*2048 + kt*128]
    const u16* kp = K + quad*512 + (kw*32 + l16)*8;
    // V frag (ct):    vp[nc*8192 + ct*128]
    const u16* vp = V + (kw*4 + quad)*1024 + l16*8;

    // Q fragments for this wave's 32 rows: 2 row-tiles x 4 k-slices
    bf8 aq[2][4];
    #pragma unroll
    for (int rt = 0; rt < 2; ++rt)
        #pragma unroll
        for (int kk = 0; kk < 4; ++kk)
            aq[rt][kk] = *reinterpret_cast<const bf8*>(
                &Q[(size_t)(m0 + rt*16 + l16)*HID + kk*32 + quad*8]);

    bf8 ones;
    #pragma unroll
    for (int j = 0; j < 8; ++j) ones[j] = (short)0x3F80;   // bf16 1.0

    f4 oacc[2][8];
    #pragma unroll
    for (int rt = 0; rt < 2; ++rt)
        #pragma unroll
        for (int ct = 0; ct < 8; ++ct) oacc[rt][ct] = f4{0,0,0,0};
    f4 sumacc[2] = {f4{0,0,0,0}, f4{0,0,0,0}};

    u16* pw = lds + wave * (32*42);            // per-wave P tile

    // prologue: K fragments for chunk 0
    bf8 kf[8];
    #pragma unroll
    for (int kk = 0; kk < 4; ++kk)
        #pragma unroll
        for (int kt = 0; kt < 2; ++kt)
            kf[kk*2+kt] = *reinterpret_cast<const bf8*>(&kp[kk*2048 + kt*128]);

    for (int nc = 0; nc < N_/64; ++nc){
        size_t off = (size_t)nc * 8192;
        // V first half (needed after the exp/P phase; L2 latency hides under it)
        bf8 vf[8];
        #pragma unroll
        for (int ct = 0; ct < 4; ++ct)
            vf[ct] = *reinterpret_cast<const bf8*>(&vp[off + ct*128]);
        // QK: rows [m0,m0+32) x keys [kw*32, kw*32+32) of chunk nc
        f4 sacc[2][2] = {{f4{0,0,0,0}, f4{0,0,0,0}}, {f4{0,0,0,0}, f4{0,0,0,0}}};
        __builtin_amdgcn_s_setprio(1);
        #pragma unroll
        for (int kk = 0; kk < 4; ++kk)
            #pragma unroll
            for (int kt = 0; kt < 2; ++kt){
                sacc[0][kt] = MFMA(aq[0][kk], kf[kk*2+kt], sacc[0][kt]);
                sacc[1][kt] = MFMA(aq[1][kk], kf[kk*2+kt], sacc[1][kt]);
            }
        __builtin_amdgcn_s_setprio(0);
        // refill K fragments for chunk nc+1 (at nc=35 this reads 16 KB past this
        // z's K region -- still inside the workspace (Vc follows Kc), never used)
        {
            size_t noff = off + 8192;
            #pragma unroll
            for (int kk = 0; kk < 4; ++kk)
                #pragma unroll
                for (int kt = 0; kt < 2; ++kt)
                    kf[kk*2+kt] = *reinterpret_cast<const bf8*>(&kp[noff + kk*2048 + kt*128]);
        }
        // p = exp2(s), truncating bf16 store to per-wave P tile
        #pragma unroll
        for (int rt = 0; rt < 2; ++rt)
            #pragma unroll
            for (int kt = 0; kt < 2; ++kt)
                #pragma unroll
                for (int r = 0; r < 4; ++r)
                    pw[(rt*16 + quad*4 + r)*42 + kt*16 + l16] = hi16(fexp2(sacc[rt][kt][r]));
        // V second half
        #pragma unroll
        for (int ct = 4; ct < 8; ++ct)
            vf[ct] = *reinterpret_cast<const bf8*>(&vp[off + ct*128]);
        // PV + rowsum over this wave's 32-key half (K-dim = 32 -> single step)
        bf8 ap[2];
        #pragma unroll
        for (int rt = 0; rt < 2; ++rt)
            ap[rt] = *reinterpret_cast<const bf8*>(&pw[(rt*16 + l16)*42 + quad*8]);
        __builtin_amdgcn_s_setprio(1);
        sumacc[0] = MFMA(ap[0], ones, sumacc[0]);
        sumacc[1] = MFMA(ap[1], ones, sumacc[1]);
        #pragma unroll
        for (int ct = 0; ct < 8; ++ct){
            oacc[0][ct] = MFMA(ap[0], vf[ct], oacc[0][ct]);
            oacc[1][ct] = MFMA(ap[1], vf[ct], oacc[1][ct]);
        }
        __builtin_amdgcn_s_setprio(0);
    }

    // ---- epilogue: reduce key-halves, normalize, out-GEMM -------------------
    __syncthreads();                           // all P-tile reads done
    float* fpo = (float*)lds;                  // 64 x 132 f32 partial O
    float* fps = (float*)((char*)lds + 33792); // 64 f32 partial rowsum
    u16*  Hm   = lds;                          // 64 x 136 u16 H tile (after fold)
    if (kw == 1){
        #pragma unroll
        for (int rt = 0; rt < 2; ++rt){
            #pragma unroll
            for (int ct = 0; ct < 8; ++ct)
                #pragma unroll
                for (int r = 0; r < 4; ++r)
                    fpo[(rw*32 + rt*16 + quad*4 + r)*132 + ct*16 + l16] = oacc[rt][ct][r];
            if (l16 == 0)
                #pragma unroll
                for (int r = 0; r < 4; ++r)
                    fps[rw*32 + rt*16 + quad*4 + r] = sumacc[rt][r];
        }
    }
    __syncthreads();
    float inv[2][4];
    if (kw == 0){
        // fold kw1's partials into registers (no LDS writes yet)
        #pragma unroll
        for (int rt = 0; rt < 2; ++rt){
            #pragma unroll
            for (int r = 0; r < 4; ++r)
                inv[rt][r] = 1.0f / (sumacc[rt][r] + fps[rw*32 + rt*16 + quad*4 + r]);
            #pragma unroll
            for (int ct = 0; ct < 8; ++ct)
                #pragma unroll
                for (int r = 0; r < 4; ++r)
                    oacc[rt][ct][r] += fpo[(rw*32 + rt*16 + quad*4 + r)*132 + ct*16 + l16];
        }
    }
    __syncthreads();                           // all fpo reads complete
    if (kw == 0){
        #pragma unroll
        for (int rt = 0; rt < 2; ++rt)
            #pragma unroll
            for (int ct = 0; ct < 8; ++ct)
                #pragma unroll
                for (int r = 0; r < 4; ++r)
                    Hm[(rw*32 + rt*16 + quad*4 + r)*136 + ct*16 + l16]
                        = f2bf(oacc[rt][ct][r] * inv[rt][r]);
    }
    __syncthreads();

    // out GEMM: wave w -> oc [w*64, w*64+64); K = HID = 128
    int mb = mt * 64;
    int oc0 = wave * 64;
    f4 acc2[4][4];
    #pragma unroll
    for (int ot = 0; ot < 4; ++ot)
        #pragma unroll
        for (int nt = 0; nt < 4; ++nt) acc2[ot][nt] = f4{0,0,0,0};
    #pragma unroll
    for (int kk = 0; kk < 4; ++kk){
        bf8 bh[4];
        #pragma unroll
        for (int nt = 0; nt < 4; ++nt)
            bh[nt] = *reinterpret_cast<const bf8*>(&Hm[(nt*16 + l16)*136 + kk*32 + quad*8]);
        #pragma unroll
        for (int ot = 0; ot < 4; ++ot){
            bf8 a = *reinterpret_cast<const bf8*>(&Wf[(oc0 + ot*16 + l16)*HID + kk*32 + quad*8]);
            #pragma unroll
            for (int nt = 0; nt < 4; ++nt)
                acc2[ot][nt] = MFMA(a, bh[nt], acc2[ot][nt]);
        }
    }
    #pragma unroll
    for (int ot = 0; ot < 4; ++ot)
        #pragma unroll
        for (int nt = 0; nt < 4; ++nt){
            int m = mb + nt*16 + l16;
            #pragma unroll
            for (int r = 0; r < 4; ++r){
                int oc = oc0 + ot*16 + quad*4 + r;
                O[(size_t)oc*N_ + m] = acc2[ot][nt][r] + bias[oc] + X[(size_t)oc*N_ + m];
            }
        }
}

// ---------------------------------------------------------------------------
extern "C" void kernel_launch(void* const* d_in, const int* in_sizes, int n_in,
                              void* d_out, int out_size, void* d_ws, size_t ws_size,
                              hipStream_t stream){
    const float* x0  = (const float*)d_in[0];
    const float* x1  = (const float*)d_in[1];
    const float* ew0 = (const float*)d_in[2];
    const float* eb0 = (const float*)d_in[3];
    const float* ew1 = (const float*)d_in[4];
    const float* eb1 = (const float*)d_in[5];
    const float* ow0 = (const float*)d_in[6];
    const float* ob0 = (const float*)d_in[7];
    const float* ow1 = (const float*)d_in[8];
    const float* ob1 = (const float*)d_in[9];

    u16* ws = (u16*)d_ws;
    const size_t QT_E = (size_t)16 * N_ * HID;
    u16* Qt   = ws;
    u16* Kc   = Qt + QT_E;
    u16* Vc   = Kc + QT_E;
    u16* Wbf  = Vc + QT_E;
    u16* weff = Wbf + (size_t)2 * O3 * C_;
    u16* Xt   = (u16*)d_out;                  // scratch phase

    k_wcvt     <<<dim3(96, 2),     dim3(256), 0, stream>>>(ew0, ew1, Wbf);
    k_weff     <<<dim3(256),       dim3(256), 0, stream>>>(ow0, ow1, weff);
    k_transpose<<<dim3(36, 4, 16), dim3(256), 0, stream>>>(x0, x1, Xt);
    k_embed    <<<dim3(36, 6, 16), dim3(256), 0, stream>>>(Xt, Wbf, eb0, eb1, Qt, Kc, Vc);
    k_attn_out <<<dim3(576),       dim3(256), 0, stream>>>(Qt, Kc, Vc, weff, ob0, ob1,
                                                           x0, x1, (float*)d_out);
}